// Round 4
// baseline (186.498 us; speedup 1.0000x reference)
//
#include <hip/hip_runtime.h>
#include <math.h>

// LSTM_55344948576591 — two-kernel implementation, R4.
// B=256, T=32, CNN_DIM=512, HW=14 (196 elems/channel), HID=8, V=37, G=4*HID=32.
//
// R4 pool: 49 float4/channel = 7x7. Lane privately sums 7 consecutive float4s
// (112 B run, 7|49 so never crosses a channel boundary); 8 lanes/channel
// (k7<7 active), 8 channels/wave/iter, 3 width-8 shfls per 8 channels.
// 1024 blocks x 256 thr -> 16 waves/CU, 7 indep loads/lane = ~100 KB
// in flight/CU. This removes R2/R3's heavy cross-lane reduce traffic and
// the 49/64 masked single-load pattern — if pooling is still ~50 us after
// this, the cap is the read medium (dirty-after-restore lines), not kernel
// structure.
// lstm_rest unchanged (proven correct, ~12 us by R1 decomposition).

#define BDIM 512

__device__ __forceinline__ float wave_reduce_sum(float v) {
#pragma unroll
    for (int off = 32; off; off >>= 1) v += __shfl_down(v, off, 64);
    return v;
}

__device__ __forceinline__ float sigf(float x) { return 1.0f / (1.0f + __expf(-x)); }
__device__ __forceinline__ float tanhfast(float x) { return 1.0f - 2.0f / (__expf(2.0f * x) + 1.0f); }

// ---------------------------------------------------------------------------
// Kernel 1: pooling. grid = 1024 x 256. 4096 waves, 8 channels/wave/iter,
// 4 iters -> 131072 channels.
// ---------------------------------------------------------------------------
__global__ __launch_bounds__(256) void pool_kernel(
    const float* __restrict__ features, float* __restrict__ pooled /* [B*C] */)
{
    const int wglobal = (blockIdx.x << 2) + (threadIdx.x >> 6);  // 0..4095
    const int lane    = threadIdx.x & 63;
    const int g       = lane >> 3;   // channel slot within wave, 0..7
    const int k7      = lane & 7;    // 0..7; k7<7 active (7 lanes x 7 float4s = 49)

    for (int i = 0; i < 4; ++i) {
        const int ch = (i << 15) + (wglobal << 3) + g;           // unique channel
        const float4* p = (const float4*)features + (size_t)ch * 49 + k7 * 7;
        float s = 0.0f;
        if (k7 < 7) {
            float4 v0 = p[0], v1 = p[1], v2 = p[2], v3 = p[3],
                   v4 = p[4], v5 = p[5], v6 = p[6];
            float a0 = (v0.x + v0.y) + (v0.z + v0.w);
            float a1 = (v1.x + v1.y) + (v1.z + v1.w);
            float a2 = (v2.x + v2.y) + (v2.z + v2.w);
            float a3 = (v3.x + v3.y) + (v3.z + v3.w);
            float a4 = (v4.x + v4.y) + (v4.z + v4.w);
            float a5 = (v5.x + v5.y) + (v5.z + v5.w);
            float a6 = (v6.x + v6.y) + (v6.z + v6.w);
            s = ((a0 + a1) + (a2 + a3)) + ((a4 + a5) + a6);
        }
        // sum the 8-lane group (lane k7==7 contributes 0)
        s += __shfl_down(s, 4, 8);
        s += __shfl_down(s, 2, 8);
        s += __shfl_down(s, 1, 8);
        if (k7 == 0) pooled[ch] = s * (1.0f / 196.0f);
    }
}

// ---------------------------------------------------------------------------
// Kernel 2: everything after pooling. grid = B, block = 512. (unchanged)
// ---------------------------------------------------------------------------
__global__ __launch_bounds__(BDIM) void lstm_rest(
    const float* __restrict__ pooled_g, const float* __restrict__ captions,
    const float* __restrict__ W_ih, const float* __restrict__ b_ih,
    const float* __restrict__ W_hh, const float* __restrict__ b_hh,
    const float* __restrict__ W_in, const float* __restrict__ b_in,
    const float* __restrict__ W_out, const float* __restrict__ b_out,
    const int* __restrict__ isTraining, float* __restrict__ out)
{
    constexpr int T = 32, V = 37, HID = 8, C = 512, G = 32;

    __shared__ float pooled[C];
    __shared__ float xs[T * V];
    __shared__ float wih[G * V];
    __shared__ float xg[T * G];
    __shared__ float hist[T * HID];
    __shared__ float lg[T * V];
    __shared__ float bsum[G];
    __shared__ float inv_s[V];

    const int b    = blockIdx.x;
    const int tid  = threadIdx.x;
    const int lane = tid & 63;
    const int w    = tid >> 6;   // 0..7

    pooled[tid] = pooled_g[(size_t)b * C + tid];
    for (int i = tid; i < G * V; i += BDIM) wih[i] = W_ih[i];
    for (int i = tid + V; i < T * V; i += BDIM) xs[i] = captions[(size_t)b * T * V + (i - V)];
    if (tid < G) bsum[tid] = b_ih[tid] + b_hh[tid];
    __syncthreads();

    // Phase B: x0 = pooled @ W_in.T + b_in
    for (int v = w; v < V; v += 8) {
        const float* wr = W_in + (size_t)v * C;
        float p = 0.0f;
#pragma unroll
        for (int k = 0; k < 8; ++k) p += pooled[lane + 64 * k] * wr[lane + 64 * k];
        p = wave_reduce_sum(p);
        if (lane == 0) xs[v] = p + b_in[v];
    }
    __syncthreads();

    // Phase C: xg[t][j] = xs[t]@W_ih.T + (b_ih+b_hh)
    for (int e = tid; e < T * G; e += BDIM) {
        const int t = e >> 5, j = e & 31;
        const float* xr = xs + t * V;
        const float* wr = wih + j * V;
        float acc = bsum[j];
#pragma unroll
        for (int v = 0; v < V; ++v) acc += xr[v] * wr[v];
        xg[e] = acc;
    }
    __syncthreads();

    // Phase D: sequential recurrence (wave 0 only)
    const bool train = (isTraining[0] != 0);
    if (w == 0) {
        const int j = lane & 31;
        const int k8 = lane & 7;
        float whh_r[HID];
#pragma unroll
        for (int k = 0; k < HID; ++k) whh_r[k] = W_hh[j * HID + k];
        float wout_r[HID];
        float bout_r = 0.0f;
        if (lane < V) {
#pragma unroll
            for (int k = 0; k < HID; ++k) wout_r[k] = W_out[lane * HID + k];
            bout_r = b_out[lane];
        }
        float h = 0.0f, c = 0.0f;
        float prevout = 0.0f;

        for (int t = 0; t < T; ++t) {
            float gate;
            if (train || t == 0) {
                gate = xg[t * G + j];
            } else {
                float acc = bsum[j];
                const float* wr = wih + j * V;
#pragma unroll
                for (int v = 0; v < V; ++v) acc += __shfl(prevout, v, 64) * wr[v];
                gate = acc;
            }
#pragma unroll
            for (int k = 0; k < HID; ++k) gate += __shfl(h, k, 64) * whh_r[k];

            const int sec = lane >> 3;              // 0:i 1:f 2:g 3:o
            const float a = (sec == 2) ? tanhfast(gate) : sigf(gate);

            const float ig = __shfl(a, k8, 64);
            const float fg = __shfl(a, 8 + k8, 64);
            const float gg = __shfl(a, 16 + k8, 64);
            const float og = __shfl(a, 24 + k8, 64);
            c = fg * c + ig * gg;
            h = og * tanhfast(c);

            if (train) {
                if (lane < HID) hist[t * HID + lane] = h;
            } else {
                float o = bout_r;
#pragma unroll
                for (int k = 0; k < HID; ++k) o += __shfl(h, k, 64) * wout_r[k];
                if (lane < V) lg[t * V + lane] = o;
                prevout = o;
            }
        }
    }
    __syncthreads();

    // Phase E: logits (training path)
    if (train) {
        for (int e = tid; e < T * V; e += BDIM) {
            const int t = e / V, v = e - t * V;
            const float* hr = hist + t * HID;
            const float* wr = W_out + v * HID;
            float acc = b_out[v];
#pragma unroll
            for (int k = 0; k < HID; ++k) acc += hr[k] * wr[k];
            lg[e] = acc;
        }
    }
    __syncthreads();

    // Phase F: softmax over TIME axis
    if (tid < V) {
        float m = -1e30f;
#pragma unroll
        for (int t = 0; t < T; ++t) m = fmaxf(m, lg[t * V + tid]);
        float s = 0.0f;
#pragma unroll
        for (int t = 0; t < T; ++t) {
            const float e = __expf(lg[t * V + tid] - m);
            lg[t * V + tid] = e;
            s += e;
        }
        inv_s[tid] = 1.0f / s;
    }
    __syncthreads();

    float* outB = out + (size_t)b * T * V;
    for (int e = tid; e < T * V; e += BDIM) {
        const int t = e / V, v = e - t * V;
        outB[e] = lg[e] * inv_s[v];
    }
}

extern "C" void kernel_launch(void* const* d_in, const int* in_sizes, int n_in,
                              void* d_out, int out_size, void* d_ws, size_t ws_size,
                              hipStream_t stream) {
    const float* features = (const float*)d_in[0];
    const float* captions = (const float*)d_in[1];
    const float* W_ih     = (const float*)d_in[2];
    const float* b_ih     = (const float*)d_in[3];
    const float* W_hh     = (const float*)d_in[4];
    const float* b_hh     = (const float*)d_in[5];
    const float* W_in     = (const float*)d_in[6];
    const float* b_in     = (const float*)d_in[7];
    const float* W_out    = (const float*)d_in[8];
    const float* b_out    = (const float*)d_in[9];
    const int*   isTrain  = (const int*)d_in[10];
    float* out = (float*)d_out;

    float* pooled = (float*)d_ws;   // [B*C] = 131072 floats = 512 KB

    pool_kernel<<<1024, 256, 0, stream>>>(features, pooled);
    lstm_rest<<<256, BDIM, 0, stream>>>(pooled, captions, W_ih, b_ih, W_hh, b_hh,
                                        W_in, b_in, W_out, b_out, isTrain, out);
}